// Round 2
// baseline (51.809 us; speedup 1.0000x reference)
//
#include <hip/hip_runtime.h>

#define ALPHA 0.2f
#define BATCH 16
#define WIN 100
#define KN 128          // number of nodes (feature channels)
#define DE 200          // embed dim

// Kernel 1: Rt[b][d][j] = sum_w input[b,w,j] * lin_w[100+w, d] + lin_b[d]
// One block per (b, j). Stored d-major so k_attn reads coalesced across j.
__global__ __launch_bounds__(256) void k_right(
    const float* __restrict__ in, const float* __restrict__ lw,
    const float* __restrict__ lb, float* __restrict__ Rt) {
  int bj = blockIdx.x;
  int b = bj >> 7, j = bj & (KN - 1);
  int t = threadIdx.x;
  __shared__ float xj[WIN];
  if (t < WIN) xj[t] = in[((size_t)b * WIN + t) * KN + j];
  __syncthreads();
  if (t < DE) {
    float acc = 0.f;
#pragma unroll 4
    for (int w = 0; w < WIN; ++w)
      acc = fmaf(xj[w], lw[(WIN + w) * DE + t], acc);
    Rt[((size_t)b * DE + t) * KN + j] = acc + lb[t];
  }
}

// Kernel 2: per (b,i): L[b,i,:] computed locally, e[j] = sum_d leaky(L+Rt)*aw,
// softmax over j, store attention transposed: at[b][j][i].
__global__ __launch_bounds__(256) void k_attn(
    const float* __restrict__ in, const float* __restrict__ lw,
    const float* __restrict__ aw, const float* __restrict__ Rt,
    float* __restrict__ at) {
  int bi = blockIdx.x;
  int b = bi >> 7, i = bi & (KN - 1);
  int t = threadIdx.x;
  __shared__ float xi[WIN];
  __shared__ float Li[DE];
  __shared__ float aws[DE];
  __shared__ float part[256];
  __shared__ float wred[4];
  if (t < WIN) xi[t] = in[((size_t)b * WIN + t) * KN + i];
  if (t < DE) aws[t] = aw[t];
  __syncthreads();
  if (t < DE) {
    float acc = 0.f;
#pragma unroll 4
    for (int w = 0; w < WIN; ++w)
      acc = fmaf(xi[w], lw[w * DE + t], acc);
    Li[t] = acc;
  }
  __syncthreads();

  // e[j]: 2 threads per j, each covers 100 of the 200 d's.
  int j = t & (KN - 1), dh = t >> 7;
  const float* rtb = Rt + (size_t)b * DE * KN;
  float acc = 0.f;
#pragma unroll 4
  for (int dd = 0; dd < 100; ++dd) {
    int d = dh * 100 + dd;
    float pre = Li[d] + rtb[d * KN + j];
    float v = pre >= 0.f ? pre : ALPHA * pre;
    acc = fmaf(v, aws[d], acc);
  }
  part[t] = acc;
  __syncthreads();
  float ej = part[j] + part[j + 128];   // every thread holds e[j], j = t&127

  // softmax over the 128 j values (waves 2,3 duplicate waves 0,1)
  float m = ej;
  for (int off = 32; off; off >>= 1) m = fmaxf(m, __shfl_xor(m, off));
  int wid = t >> 6;
  if ((t & 63) == 0) wred[wid] = m;
  __syncthreads();
  m = fmaxf(fmaxf(wred[0], wred[1]), fmaxf(wred[2], wred[3]));
  float p = __expf(ej - m);
  float s = p;
  for (int off = 32; off; off >>= 1) s += __shfl_xor(s, off);
  __syncthreads();
  if ((t & 63) == 0) wred[wid] = s;
  __syncthreads();
  s = wred[0] + wred[1];                // waves 0+1 cover all 128 j exactly once
  if (t < 128) at[((size_t)b * KN + j) * KN + i] = p / s;
}

// Kernel 3: per (b,w): out[b,w,i] = sigmoid(sum_j at[b,j,i] * in[b,w,j])
__global__ __launch_bounds__(128) void k_out(
    const float* __restrict__ in, const float* __restrict__ at,
    float* __restrict__ out) {
  int bw = blockIdx.x;
  int b = bw / WIN, w = bw % WIN;
  int i = threadIdx.x;
  __shared__ float xr[KN];
  xr[i] = in[((size_t)b * WIN + w) * KN + i];
  __syncthreads();
  const float* atb = at + (size_t)b * KN * KN;
  float acc = 0.f;
#pragma unroll 8
  for (int jj = 0; jj < KN; ++jj)
    acc = fmaf(xr[jj], atb[jj * KN + i], acc);
  float sig = 1.f / (1.f + __expf(-acc));
  out[((size_t)b * WIN + w) * KN + i] = sig;
}

extern "C" void kernel_launch(void* const* d_in, const int* in_sizes, int n_in,
                              void* d_out, int out_size, void* d_ws, size_t ws_size,
                              hipStream_t stream) {
  const float* in = (const float*)d_in[0];   // (16,100,128)
  const float* lw = (const float*)d_in[1];   // (200,200)
  const float* lb = (const float*)d_in[2];   // (200,)
  const float* aw = (const float*)d_in[3];   // (200,)
  float* out = (float*)d_out;                // (16,100,128)

  float* Rt = (float*)d_ws;                          // BATCH*DE*KN = 409600 floats
  float* at = Rt + (size_t)BATCH * DE * KN;          // BATCH*KN*KN = 262144 floats

  k_right<<<BATCH * KN, 256, 0, stream>>>(in, lw, lb, Rt);
  k_attn <<<BATCH * KN, 256, 0, stream>>>(in, lw, aw, Rt, at);
  k_out  <<<BATCH * WIN, 128, 0, stream>>>(in, at, out);
}

// Round 3
// 32.251 us; speedup vs baseline: 1.6064x; 1.6064x over previous
//
#include <hip/hip_runtime.h>

#define ALPHA 0.2f
#define BATCH 16
#define WIN 100
#define KN 128          // number of nodes
#define DE 200          // embed dim
#define JT 8            // j-tile in k_lin
#define IT 4            // i-tile in k_attn_out

// Kernel 1: per (b, 8-j tile): read lin_w ONCE, compute
//   L[b][j][d]  = sum_w input[b,w,j]*lw[w,d]              (row-major, via LDS transpose)
//   Rt[b][d][j] = sum_w input[b,w,j]*lw[100+w,d] + lb[d]  (d-major for coalesced j reads)
__global__ __launch_bounds__(256) void k_lin(
    const float* __restrict__ in, const float* __restrict__ lw,
    const float* __restrict__ lb, float* __restrict__ Rt, float* __restrict__ L) {
  int blk = blockIdx.x;
  int b = blk >> 4, jt = blk & 15;
  int j0 = jt * JT;
  int t = threadIdx.x;
  __shared__ float xs[WIN][JT];
  __shared__ float ls[JT][DE];
  for (int idx = t; idx < WIN * JT; idx += 256) {
    int w = idx >> 3, jj = idx & (JT - 1);
    xs[w][jj] = in[((size_t)b * WIN + w) * KN + j0 + jj];
  }
  __syncthreads();
  if (t < DE) {
    float la[JT] = {}, ra[JT] = {};
    for (int w = 0; w < WIN; ++w) {
      float w1 = lw[w * DE + t];
      float w2 = lw[(WIN + w) * DE + t];
#pragma unroll
      for (int jj = 0; jj < JT; ++jj) {
        la[jj] = fmaf(xs[w][jj], w1, la[jj]);
        ra[jj] = fmaf(xs[w][jj], w2, ra[jj]);
      }
    }
    float bias = lb[t];
    float* rtp = Rt + ((size_t)b * DE + t) * KN + j0;
#pragma unroll
    for (int jj = 0; jj < JT; ++jj) {
      rtp[jj] = ra[jj] + bias;
      ls[jj][t] = la[jj];
    }
  }
  __syncthreads();
  for (int idx = t; idx < JT * DE; idx += 256) {
    int row = idx / DE, col = idx % DE;
    L[((size_t)b * KN + j0 + row) * DE + col] = ls[row][col];
  }
}

// Kernel 2: per (b, 4-i tile): e[ii][j] = sum_d leaky(L[i]+Rt[d][j])*aw[d],
// wave-per-row softmax over j, then fused PV + sigmoid + transposed store.
__global__ __launch_bounds__(256) void k_attn_out(
    const float* __restrict__ in, const float* __restrict__ aw,
    const float* __restrict__ Rt, const float* __restrict__ L,
    float* __restrict__ out) {
  int blk = blockIdx.x;
  int b = blk >> 5, it = blk & 31;
  int i0 = it * IT;
  int t = threadIdx.x;
  __shared__ float xs[KN][WIN];        // xs[j][w] = input[b][w][j] (transposed)
  __shared__ float Lis[IT][DE];
  __shared__ float aws[DE];
  __shared__ float part[2][IT][KN];
  __shared__ float ats[IT][KN];

  const float* inb = in + (size_t)b * WIN * KN;
  for (int idx = t; idx < WIN * KN; idx += 256) {
    int w = idx >> 7, j = idx & (KN - 1);
    xs[j][w] = inb[idx];               // coalesced read, transposed LDS write
  }
  for (int idx = t; idx < IT * DE; idx += 256) {
    int ii = idx / DE, d = idx % DE;
    Lis[ii][d] = L[((size_t)b * KN + i0 + ii) * DE + d];
  }
  if (t < DE) aws[t] = aw[t];
  __syncthreads();

  // e-phase: thread (j, dh) covers 100 d's for 4 i's
  int j = t & (KN - 1), dh = t >> 7;
  const float* rtb = Rt + (size_t)b * DE * KN;
  float acc[IT] = {};
  for (int dd = 0; dd < 100; ++dd) {
    int d = dh * 100 + dd;
    float r = rtb[d * KN + j];
    float a = aws[d];
#pragma unroll
    for (int ii = 0; ii < IT; ++ii) {
      float pre = Lis[ii][d] + r;
      float v = fmaf(fminf(pre, 0.f), -(1.f - ALPHA), pre);  // leaky relu
      acc[ii] = fmaf(v, a, acc[ii]);
    }
  }
#pragma unroll
  for (int ii = 0; ii < IT; ++ii) part[dh][ii][j] = acc[ii];
  __syncthreads();

  // softmax: wave r owns row r (64 lanes x 2 j's each)
  {
    int r = t >> 6, l = t & 63;
    float e0 = part[0][r][l] + part[1][r][l];
    float e1 = part[0][r][l + 64] + part[1][r][l + 64];
    float m = fmaxf(e0, e1);
    for (int off = 32; off; off >>= 1) m = fmaxf(m, __shfl_xor(m, off));
    float p0 = __expf(e0 - m), p1 = __expf(e1 - m);
    float s = p0 + p1;
    for (int off = 32; off; off >>= 1) s += __shfl_xor(s, off);
    float inv = 1.f / s;
    ats[r][l] = p0 * inv;
    ats[r][l + 64] = p1 * inv;
  }
  __syncthreads();

  // PV: thread (w, ih) computes out[b][w][i0 + ih*2 + {0,1}]
  if (t < 2 * WIN) {
    int w = t >> 1, ih = t & 1;
    float a0 = 0.f, a1 = 0.f;
#pragma unroll 8
    for (int jj = 0; jj < KN; ++jj) {
      float x = xs[jj][w];
      a0 = fmaf(ats[ih * 2 + 0][jj], x, a0);
      a1 = fmaf(ats[ih * 2 + 1][jj], x, a1);
    }
    float s0 = 1.f / (1.f + __expf(-a0));
    float s1 = 1.f / (1.f + __expf(-a1));
    *reinterpret_cast<float2*>(&out[((size_t)b * WIN + w) * KN + i0 + ih * 2]) =
        make_float2(s0, s1);
  }
}

extern "C" void kernel_launch(void* const* d_in, const int* in_sizes, int n_in,
                              void* d_out, int out_size, void* d_ws, size_t ws_size,
                              hipStream_t stream) {
  const float* in = (const float*)d_in[0];   // (16,100,128)
  const float* lw = (const float*)d_in[1];   // (200,200)
  const float* lb = (const float*)d_in[2];   // (200,)
  const float* aw = (const float*)d_in[3];   // (200,)
  float* out = (float*)d_out;                // (16,100,128)

  float* Rt = (float*)d_ws;                          // 16*200*128 floats
  float* L  = Rt + (size_t)BATCH * DE * KN;          // 16*128*200 floats

  k_lin     <<<BATCH * 16, 256, 0, stream>>>(in, lw, lb, Rt, L);
  k_attn_out<<<BATCH * 32, 256, 0, stream>>>(in, aw, Rt, L, out);
}

// Round 4
// 28.663 us; speedup vs baseline: 1.8075x; 1.1252x over previous
//
#include <hip/hip_runtime.h>

#define ALPHA 0.2f
#define BATCH 16
#define WIN 100
#define KN 128          // nodes
#define DE 200          // embed dim
#define DT 8            // d-tile in k_lin  (25 tiles)
#define IT 8            // i-tile in k_attn_out (16 tiles)

// Kernel A: per (b, 8-d tile): stage X[b] (50 KB) + lw slice (1.6 KB) in LDS,
// inner loop is pure-LDS. Outputs d-major:
//   Rt[b][d][j] = sum_w x[w][j]*lw[100+w][d] + lb[d]
//   Lt[b][d][j] = sum_w x[w][j]*lw[w][d]
__global__ __launch_bounds__(256) void k_lin(
    const float* __restrict__ in, const float* __restrict__ lw,
    const float* __restrict__ lb, float* __restrict__ Rt, float* __restrict__ Lt) {
  int blk = blockIdx.x;
  int b = blk / 25, dt = blk % 25;
  int d0 = dt * DT;
  int t = threadIdx.x;
  __shared__ float xs[WIN * KN];           // [w][j]
  __shared__ float lws[2 * WIN * DT];      // [half][w][dd], rows of 32B
  const float* inb = in + (size_t)b * WIN * KN;
  for (int i4 = t; i4 < WIN * KN / 4; i4 += 256)
    reinterpret_cast<float4*>(xs)[i4] = reinterpret_cast<const float4*>(inb)[i4];
  for (int idx = t; idx < 2 * WIN * DT; idx += 256) {
    int half = idx >= WIN * DT;
    int rem = idx - half * WIN * DT;
    int w = rem >> 3, c = rem & 7;
    lws[idx] = lw[(half * WIN + w) * DE + d0 + c];
  }
  __syncthreads();

  int j = t & (KN - 1), du = t >> 7;       // du in {0,1}: 4 d's each
  float la[4] = {}, ra[4] = {};
  for (int w = 0; w < WIN; ++w) {
    float x = xs[w * KN + j];
    float4 wl = *reinterpret_cast<const float4*>(&lws[w * DT + du * 4]);
    float4 wr = *reinterpret_cast<const float4*>(&lws[WIN * DT + w * DT + du * 4]);
    la[0] = fmaf(x, wl.x, la[0]); la[1] = fmaf(x, wl.y, la[1]);
    la[2] = fmaf(x, wl.z, la[2]); la[3] = fmaf(x, wl.w, la[3]);
    ra[0] = fmaf(x, wr.x, ra[0]); ra[1] = fmaf(x, wr.y, ra[1]);
    ra[2] = fmaf(x, wr.z, ra[2]); ra[3] = fmaf(x, wr.w, ra[3]);
  }
  int dbase = d0 + du * 4;
#pragma unroll
  for (int k = 0; k < 4; ++k) {
    int d = dbase + k;
    Rt[((size_t)b * DE + d) * KN + j] = ra[k] + lb[d];
    Lt[((size_t)b * DE + d) * KN + j] = la[k];
  }
}

// Kernel B: per (b, 8-i tile), 512 threads:
//   e[ii][j] = sum_d leaky(Lt[d][i0+ii] + Rt[d][j]) * aw[d]   (d split 4-way)
//   softmax: wave r owns row r; PV + sigmoid + store.
__global__ __launch_bounds__(512) void k_attn_out(
    const float* __restrict__ in, const float* __restrict__ aw,
    const float* __restrict__ Rt, const float* __restrict__ Lt,
    float* __restrict__ out) {
  int blk = blockIdx.x;
  int b = blk >> 4, it = blk & 15;
  int i0 = it * IT;
  int t = threadIdx.x;
  __shared__ float xs[WIN * 129];          // [w][j] padded: odd stride
  __shared__ float Lis[DE][IT];            // [d][ii], 32B rows
  __shared__ float aws[DE];
  __shared__ float part[4][IT][KN];
  __shared__ float ats[IT][132];

  const float* inb = in + (size_t)b * WIN * KN;
  for (int idx = t; idx < WIN * KN; idx += 512) {
    int w = idx >> 7, j = idx & (KN - 1);
    xs[w * 129 + j] = inb[idx];
  }
  const float* ltb = Lt + (size_t)b * DE * KN;
  for (int idx = t; idx < DE * IT; idx += 512) {
    int d = idx >> 3, ii = idx & 7;
    Lis[d][ii] = ltb[d * KN + i0 + ii];
  }
  if (t < DE) aws[t] = aw[t];
  __syncthreads();

  // e-phase: thread (j, dh) covers 50 d's for 8 i's
  {
    int j = t & (KN - 1), dh = t >> 7;     // dh in 0..3
    const float* rtb = Rt + (size_t)b * DE * KN;
    float acc[IT] = {};
#pragma unroll 5
    for (int dd = 0; dd < 50; ++dd) {
      int d = dh * 50 + dd;
      float r = rtb[d * KN + j];
      float a = aws[d];
      float4 L0 = *reinterpret_cast<const float4*>(&Lis[d][0]);
      float4 L1 = *reinterpret_cast<const float4*>(&Lis[d][4]);
      float Lv[8] = {L0.x, L0.y, L0.z, L0.w, L1.x, L1.y, L1.z, L1.w};
#pragma unroll
      for (int ii = 0; ii < IT; ++ii) {
        float pre = Lv[ii] + r;
        float v = fmaf(fminf(pre, 0.f), -(1.f - ALPHA), pre);
        acc[ii] = fmaf(v, a, acc[ii]);
      }
    }
#pragma unroll
    for (int ii = 0; ii < IT; ++ii) part[dh][ii][j] = acc[ii];
  }
  __syncthreads();

  // softmax: wave r (of 8) owns row r; 64 lanes x 2 j's
  {
    int r = t >> 6, l = t & 63;
    float e0 = part[0][r][l] + part[1][r][l] + part[2][r][l] + part[3][r][l];
    float e1 = part[0][r][l + 64] + part[1][r][l + 64] + part[2][r][l + 64] + part[3][r][l + 64];
    float m = fmaxf(e0, e1);
    for (int off = 32; off; off >>= 1) m = fmaxf(m, __shfl_xor(m, off));
    float p0 = __expf(e0 - m), p1 = __expf(e1 - m);
    float s = p0 + p1;
    for (int off = 32; off; off >>= 1) s += __shfl_xor(s, off);
    float inv = 1.f / s;
    ats[r][l] = p0 * inv;
    ats[r][l + 64] = p1 * inv;
  }
  __syncthreads();

  // PV: thread (w, q) computes out[b][w][i0 + q*2 + {0,1}], t < 400
  if (t < 4 * WIN) {
    int w = t >> 2, q = t & 3;
    float a0 = 0.f, a1 = 0.f;
#pragma unroll 8
    for (int j = 0; j < KN; ++j) {
      float x = xs[w * 129 + j];
      a0 = fmaf(ats[q * 2 + 0][j], x, a0);
      a1 = fmaf(ats[q * 2 + 1][j], x, a1);
    }
    float s0 = 1.f / (1.f + __expf(-a0));
    float s1 = 1.f / (1.f + __expf(-a1));
    *reinterpret_cast<float2*>(&out[((size_t)b * WIN + w) * KN + i0 + q * 2]) =
        make_float2(s0, s1);
  }
}

extern "C" void kernel_launch(void* const* d_in, const int* in_sizes, int n_in,
                              void* d_out, int out_size, void* d_ws, size_t ws_size,
                              hipStream_t stream) {
  const float* in = (const float*)d_in[0];   // (16,100,128)
  const float* lw = (const float*)d_in[1];   // (200,200)
  const float* lb = (const float*)d_in[2];   // (200,)
  const float* aw = (const float*)d_in[3];   // (200,)
  float* out = (float*)d_out;                // (16,100,128)

  float* Rt = (float*)d_ws;                          // 16*200*128
  float* Lt = Rt + (size_t)BATCH * DE * KN;          // 16*200*128

  k_lin     <<<BATCH * 25, 256, 0, stream>>>(in, lw, lb, Rt, Lt);
  k_attn_out<<<BATCH * 16, 512, 0, stream>>>(in, aw, Rt, Lt, out);
}